// Round 8
// baseline (39.452 us; speedup 1.0000x reference)
//
#include <hip/hip_runtime.h>

#define NB 8
#define NT 1024
#define NK 8
#define NL 1024
#define NH 256
#define NE 128
#define NF 64
#define NV 23

typedef __attribute__((ext_vector_type(8))) short bf16x8;
typedef __attribute__((ext_vector_type(4))) float f32x4;

__device__ __forceinline__ unsigned cvt_pk_bf16(float lo, float hi) {
  unsigned r;
  asm("v_cvt_pk_bf16_f32 %0, %1, %2" : "=v"(r) : "v"(lo), "v"(hi));
  return r;
}

__device__ __forceinline__ uint4 pack8(const float4 f0, const float4 f1) {
  uint4 u;
  u.x = cvt_pk_bf16(f0.x, f0.y);
  u.y = cvt_pk_bf16(f0.z, f0.w);
  u.z = cvt_pk_bf16(f1.x, f1.y);
  u.w = cvt_pk_bf16(f1.z, f1.w);
  return u;
}

// ---------------------------------------------------------------------------
// Prep: two pre-swizzled bf16 images of W1 slices (chunk = 8 k x 1 n, 16 B).
//  imgEx (4096 chunks): g in [0,16)  -> W1 rows 256+g*8..+7   (ex slice)
//  imgB (10240 chunks): g in [0,32)  -> W1 rows g*8..+7       (hs slice)
//                       g in [32,40) -> W1 rows 384+(g-32)*8  (col slice)
//  chunk address: g*256 + (n ^ (g&7)).
// ---------------------------------------------------------------------------
__global__ __launch_bounds__(64) void k_prep(const float* __restrict__ W1,
                                             uint4* __restrict__ imgEx,
                                             uint4* __restrict__ imgB) {
  const int c = blockIdx.x * 64 + threadIdx.x;  // 3584 slots of 4 chunks
  int g, n0, wrow0;
  uint4* img;
  if (c < 1024) {
    g = c >> 6; n0 = (c & 63) * 4;
    wrow0 = NH + g * 8;
    img = imgEx;
  } else {
    const int c2 = c - 1024;
    g = c2 >> 6; n0 = (c2 & 63) * 4;
    wrow0 = (g < 32) ? g * 8 : 384 + (g - 32) * 8;
    img = imgB;
  }
  float4 r[8];
#pragma unroll
  for (int j = 0; j < 8; ++j)
    r[j] = *(const float4*)&W1[(size_t)(wrow0 + j) * NH + n0];
  const float* rf = (const float*)r;
#pragma unroll
  for (int d = 0; d < 4; ++d) {
    uint4 u;
    u.x = cvt_pk_bf16(rf[0 * 4 + d], rf[1 * 4 + d]);
    u.y = cvt_pk_bf16(rf[2 * 4 + d], rf[3 * 4 + d]);
    u.z = cvt_pk_bf16(rf[4 * 4 + d], rf[5 * 4 + d]);
    u.w = cvt_pk_bf16(rf[6 * 4 + d], rf[7 * 4 + d]);
    img[g * 256 + ((n0 + d) ^ (g & 7))] = u;
  }
}

// ---------------------------------------------------------------------------
// Mega (N-split): block = (b, 16 t rows) x 128-col half nh. 4 waves, 40 KB LDS.
//  bid -> nh = (bid>>3)&1, tau = (bid&7)|((bid>>4)<<3)  (the two nh-halves of a
//  tau share bid%8 -> same XCD -> the duplicated ex gather hits that XCD's L2).
//   phase 1: stage Bs half-image (32 KB) via global_load_lds
//   phase 2: base half U[16][128] (M=16 frag, B from L2 imgB) -> swizzled Ub
//   phase 3: issue lane-private ex gather (2 rows x 256 B), pack to bf16
//   barrier
//   phase 4: ex MFMA: wave w rows w*32..+31 (2 row-frags), 8 n-frags, 4 ks;
//            B-frag read once, used twice (LDS bytes halved vs R6)
//   phase 5: partial epilogue: p = relu(acc+Ub).W2half, lg-reduce, -> Spart
// ---------------------------------------------------------------------------
__global__ __launch_bounds__(256, 3) void k_mega(
    const float* __restrict__ hs, const float* __restrict__ ex,
    const float* __restrict__ col, const int* __restrict__ c_t,
    const uint4* __restrict__ imgEx, const uint4* __restrict__ imgB,
    const float* __restrict__ b1, const float* __restrict__ W2,
    float* __restrict__ Spart) {
  extern __shared__ uint4 smem[];
  uint4* Bs = smem;          // 2048 chunks = 32 KB (half image)
  uint4* Ub = smem + 2048;   // 512 chunks = 8 KB: row*32 + (slot ^ row)

  const int tid = threadIdx.x;
  const int lane = tid & 63;
  const int w = tid >> 6;    // 0..3
  const int lm = lane & 15;
  const int lg = lane >> 4;
  const int bid = blockIdx.x;
  const int nh = (bid >> 3) & 1;
  const int tau = (bid & 7) | ((bid >> 4) << 3);
  const int b = tau >> 6;
  const int t0 = (tau & 63) * 16;

  // ---- phase 1: stage half of W1ex image (2048 chunks, linear) ----
#pragma unroll
  for (int it = 0; it < 8; ++it) {
    const int off = it * 256 + tid;       // dst chunk; lane-linear per wave
    const int g = off >> 7;
    const int nl = off & 127;
    __builtin_amdgcn_global_load_lds(
        (const __attribute__((address_space(1))) void*)(
            imgEx + g * 256 + nh * 128 + nl),
        (__attribute__((address_space(3))) void*)(Bs + off), 16, 0, 0);
  }

  // ---- phase 2: base half, M=16, batched global loads -> swizzled Ub ----
  {
    const int myt = t0 + lm;
    const int ctv2 = c_t[b * NT + myt];
    const int myc = ctv2 < 0 ? 0 : ctv2;
    f32x4 accB[2];
#pragma unroll
    for (int f = 0; f < 2; ++f) {
      const float4 bv = *(const float4*)&b1[nh * 128 + (w * 2 + f) * 16 + lg * 4];
      accB[f][0] = bv.x; accB[f][1] = bv.y; accB[f][2] = bv.z; accB[f][3] = bv.w;
    }
#pragma unroll
    for (int hb = 0; hb < 2; ++hb) {
      float4 f0a[5], f1a[5];
      uint4 bb[10];
#pragma unroll
      for (int i = 0; i < 5; ++i) {
        const int gk = (hb * 5 + i) * 4 + lg;  // 0..39
        const float* asrc = (gk < 32)
            ? &hs[((size_t)b * NT + myt) * NH + gk * 8]
            : &col[((size_t)b * NL + myc) * NF + (gk - 32) * 8];
        f0a[i] = *(const float4*)asrc;
        f1a[i] = *(const float4*)(asrc + 4);
      }
#pragma unroll
      for (int i = 0; i < 5; ++i) {
        const int gk = (hb * 5 + i) * 4 + lg;
#pragma unroll
        for (int f = 0; f < 2; ++f) {
          const int nloc = (w * 2 + f) * 16 + lm;
          bb[i * 2 + f] = imgB[(size_t)gk * 256 + nh * 128 + (nloc ^ (gk & 7))];
        }
      }
#pragma unroll
      for (int i = 0; i < 5; ++i) {
        union { uint4 u; bf16x8 v; } A;
        A.u = pack8(f0a[i], f1a[i]);
#pragma unroll
        for (int f = 0; f < 2; ++f) {
          union { uint4 u; bf16x8 v; } B2;
          B2.u = bb[i * 2 + f];
          accB[f] = __builtin_amdgcn_mfma_f32_16x16x32_bf16(B2.v, A.v, accB[f], 0, 0, 0);
        }
      }
    }
#pragma unroll
    for (int f = 0; f < 2; ++f) {
      union { uint4 u; f32x4 v; } o;
      o.v = accB[f];
      Ub[lm * 32 + (((w * 2 + f) * 4 + lg) ^ lm)] = o.u;
    }
  }

  // ---- phase 3: lane-private ex gather (rows w*32+lm and +16), pack bf16 ----
  const int ttA = w * 4 + (lm >> 3);     // t_local for row set A
  const int ttB = ttA + 2;               // for row set B
  const int kk = lm & 7;
  const int ctA = c_t[b * NT + t0 + ttA];
  const int ctB = c_t[b * NT + t0 + ttB];
  const int cA = ctA < 0 ? 0 : ctA;
  const int cB = ctB < 0 ? 0 : ctB;
  const float* rowA = &ex[(((size_t)b * NK + kk) * NL + cA) * NE];
  const float* rowB = &ex[(((size_t)b * NK + kk) * NL + cB) * NE];

  uint4 aA[4], aB[4];
  {
    float4 fa[8], fb[8];
#pragma unroll
    for (int ks = 0; ks < 4; ++ks) {
      const int g = ks * 4 + lg;
      fa[2 * ks] = *(const float4*)(rowA + g * 8);
      fa[2 * ks + 1] = *(const float4*)(rowA + g * 8 + 4);
      fb[2 * ks] = *(const float4*)(rowB + g * 8);
      fb[2 * ks + 1] = *(const float4*)(rowB + g * 8 + 4);
    }
#pragma unroll
    for (int ks = 0; ks < 4; ++ks) {
      aA[ks] = pack8(fa[2 * ks], fa[2 * ks + 1]);
      aB[ks] = pack8(fb[2 * ks], fb[2 * ks + 1]);
    }
  }

  __syncthreads();

  // ---- phase 4: ex MFMA (half-N), B-frag reused for both row sets ----
  f32x4 acc0[8] = {}, acc1[8] = {};
#pragma unroll
  for (int ks = 0; ks < 4; ++ks) {
    const int g = ks * 4 + lg;
    union { uint4 u; bf16x8 v; } A0, A1;
    A0.u = aA[ks]; A1.u = aB[ks];
#pragma unroll
    for (int fn = 0; fn < 8; ++fn) {
      const bf16x8 bfr = *(const bf16x8*)&Bs[g * 128 + ((fn * 16 + lm) ^ (g & 7))];
      acc0[fn] = __builtin_amdgcn_mfma_f32_16x16x32_bf16(bfr, A0.v, acc0[fn], 0, 0, 0);
      acc1[fn] = __builtin_amdgcn_mfma_f32_16x16x32_bf16(bfr, A1.v, acc1[fn], 0, 0, 0);
    }
  }

  // ---- phase 5: partial scores -> Spart ----
#pragma unroll
  for (int set = 0; set < 2; ++set) {
    const int tt = set ? ttB : ttA;
    f32x4* acc = set ? acc1 : acc0;
    float p = 0.f;
#pragma unroll
    for (int fn = 0; fn < 8; ++fn) {
      union { uint4 u; f32x4 v; } ubv;
      ubv.u = Ub[tt * 32 + ((fn * 4 + lg) ^ tt)];
      const float4 w2v = *(const float4*)&W2[nh * 128 + fn * 16 + lg * 4];
      p += fmaxf(acc[fn][0] + ubv.v[0], 0.f) * w2v.x +
           fmaxf(acc[fn][1] + ubv.v[1], 0.f) * w2v.y +
           fmaxf(acc[fn][2] + ubv.v[2], 0.f) * w2v.z +
           fmaxf(acc[fn][3] + ubv.v[3], 0.f) * w2v.w;
    }
    p += __shfl_xor(p, 16);
    p += __shfl_xor(p, 32);
    if (lg == 0)
      Spart[(((size_t)b * NT + t0 + tt) * NK + kk) * 2 + nh] = p;
  }
}

// ---------------------------------------------------------------------------
// Final: one thread per (b,t): sum halves, softmax over k, lambda + p_copy.
// ---------------------------------------------------------------------------
__global__ __launch_bounds__(256) void k_fin(const float* __restrict__ Spart,
                                             const int* __restrict__ c_t,
                                             const int* __restrict__ aa_ids,
                                             const float* __restrict__ b2,
                                             float* __restrict__ p_copy,
                                             float* __restrict__ lam) {
  const int bt = blockIdx.x * 256 + threadIdx.x;
  const int b = bt >> 10;
  const int ctv = c_t[bt];
  const bool valid = ctv >= 0;
  const int c = valid ? ctv : 0;
  const float b2v = b2[0];

  float4 q[4];
#pragma unroll
  for (int j = 0; j < 4; ++j) q[j] = *(const float4*)&Spart[(size_t)bt * 16 + j * 4];

  float sc[NK];
#pragma unroll
  for (int j = 0; j < 4; ++j) {
    sc[j * 2] = q[j].x + q[j].y + b2v;
    sc[j * 2 + 1] = q[j].z + q[j].w + b2v;
  }

  float mx = sc[0];
#pragma unroll
  for (int k = 1; k < NK; ++k) mx = fmaxf(mx, sc[k]);
  float wgt[NK], s = 0.f;
#pragma unroll
  for (int k = 0; k < NK; ++k) {
    wgt[k] = __expf(sc[k] - mx);
    s += wgt[k];
  }
  const float inv = valid ? (1.f / s) : 0.f;
#pragma unroll
  for (int k = 0; k < NK; ++k) wgt[k] *= inv;

  *(float4*)&lam[(size_t)bt * NK] = make_float4(wgt[0], wgt[1], wgt[2], wgt[3]);
  *(float4*)&lam[(size_t)bt * NK + 4] = make_float4(wgt[4], wgt[5], wgt[6], wgt[7]);

  int aa[NK];
#pragma unroll
  for (int k = 0; k < NK; ++k) aa[k] = aa_ids[((size_t)b * NK + k) * NL + c];

#pragma unroll
  for (int v = 0; v < NV; ++v) {
    float pc = 0.f;
#pragma unroll
    for (int k = 0; k < NK; ++k) pc += (aa[k] == v) ? wgt[k] : 0.f;
    p_copy[(size_t)bt * NV + v] = pc;
  }
}

extern "C" void kernel_launch(void* const* d_in, const int* in_sizes, int n_in,
                              void* d_out, int out_size, void* d_ws, size_t ws_size,
                              hipStream_t stream) {
  const float* hs = (const float*)d_in[0];
  const float* ex = (const float*)d_in[1];
  const float* col = (const float*)d_in[2];
  const int* ct = (const int*)d_in[3];
  const int* aa = (const int*)d_in[4];
  const float* W1 = (const float*)d_in[5];
  const float* b1 = (const float*)d_in[6];
  const float* W2 = (const float*)d_in[7];
  const float* b2 = (const float*)d_in[8];

  uint4* imgEx = (uint4*)d_ws;                       // 64 KB
  uint4* imgB = imgEx + 4096;                        // 160 KB
  float* Spart = (float*)(imgB + 10240);             // 512 KB

  float* p_copy = (float*)d_out;
  float* lam = p_copy + (size_t)NB * NT * NV;

  const size_t lds_bytes = (2048 + 512) * sizeof(uint4);  // 40 KB

  k_prep<<<56, 64, 0, stream>>>(W1, imgEx, imgB);
  k_mega<<<1024, 256, lds_bytes, stream>>>(hs, ex, col, ct, imgEx, imgB, b1,
                                           W2, Spart);
  k_fin<<<32, 256, 0, stream>>>(Spart, ct, aa, b2, p_copy, lam);
}

// Round 9
// 31.733 us; speedup vs baseline: 1.2433x; 1.2433x over previous
//
#include <hip/hip_runtime.h>

#define NB 8
#define NT 1024
#define NK 8
#define NL 1024
#define NH 256
#define NE 128
#define NF 64
#define NV 23

typedef __attribute__((ext_vector_type(8))) short bf16x8;
typedef __attribute__((ext_vector_type(4))) float f32x4;

__device__ __forceinline__ unsigned cvt_pk_bf16(float lo, float hi) {
  unsigned r;
  asm("v_cvt_pk_bf16_f32 %0, %1, %2" : "=v"(r) : "v"(lo), "v"(hi));
  return r;
}

__device__ __forceinline__ uint4 pack8(const float4 f0, const float4 f1) {
  uint4 u;
  u.x = cvt_pk_bf16(f0.x, f0.y);
  u.y = cvt_pk_bf16(f0.z, f0.w);
  u.z = cvt_pk_bf16(f1.x, f1.y);
  u.w = cvt_pk_bf16(f1.z, f1.w);
  return u;
}

// ---------------------------------------------------------------------------
// Prep: two pre-swizzled bf16 images of W1 slices (chunk = 8 k x 1 n, 16 B).
//  imgEx (4096 chunks): g in [0,16)  -> W1 rows 256+g*8..+7   (ex slice)
//  imgB (10240 chunks): g in [0,32)  -> W1 rows g*8..+7       (hs slice)
//                       g in [32,40) -> W1 rows 384+(g-32)*8  (col slice)
//  chunk address: g*256 + (n ^ (g&7)).
// ---------------------------------------------------------------------------
__global__ __launch_bounds__(64) void k_prep(const float* __restrict__ W1,
                                             uint4* __restrict__ imgEx,
                                             uint4* __restrict__ imgB) {
  const int c = blockIdx.x * 64 + threadIdx.x;  // 3584 slots of 4 chunks
  int g, n0, wrow0;
  uint4* img;
  if (c < 1024) {
    g = c >> 6; n0 = (c & 63) * 4;
    wrow0 = NH + g * 8;
    img = imgEx;
  } else {
    const int c2 = c - 1024;
    g = c2 >> 6; n0 = (c2 & 63) * 4;
    wrow0 = (g < 32) ? g * 8 : 384 + (g - 32) * 8;
    img = imgB;
  }
  float4 r[8];
#pragma unroll
  for (int j = 0; j < 8; ++j)
    r[j] = *(const float4*)&W1[(size_t)(wrow0 + j) * NH + n0];
  const float* rf = (const float*)r;
#pragma unroll
  for (int d = 0; d < 4; ++d) {
    uint4 u;
    u.x = cvt_pk_bf16(rf[0 * 4 + d], rf[1 * 4 + d]);
    u.y = cvt_pk_bf16(rf[2 * 4 + d], rf[3 * 4 + d]);
    u.z = cvt_pk_bf16(rf[4 * 4 + d], rf[5 * 4 + d]);
    u.w = cvt_pk_bf16(rf[6 * 4 + d], rf[7 * 4 + d]);
    img[g * 256 + ((n0 + d) ^ (g & 7))] = u;
  }
}

// ---------------------------------------------------------------------------
// Mega kernel: block = (b, 16 t rows), 8 waves, LDS = 80 KB -> 2 blocks/CU.
// b = bid&7 (XCD-affine: ex[b] pinned in that XCD's 4 MB L2).
//   issue base-hb0 loads -> issue global_load_lds staging (8/wave) ->
//   base hb0 compute (vmcnt(8): stage stays in flight) -> base hb1 ->
//   Ub write -> ex gather + pack -> barrier ->
//   phase 4: TWO sequential half-N passes (acc[8] each, 32 VGPR) with the
//   partial relu.W2 dot folded in -> shfl reduce -> softmax -> stores.
// launch_bounds(512,4) caps VGPR at 128 so 2 blocks/CU actually happen.
// ---------------------------------------------------------------------------
__global__ __launch_bounds__(512, 4) void k_mega(
    const float* __restrict__ hs, const float* __restrict__ ex,
    const float* __restrict__ col, const int* __restrict__ c_t,
    const int* __restrict__ aa_ids, const uint4* __restrict__ imgEx,
    const uint4* __restrict__ imgB, const float* __restrict__ b1,
    const float* __restrict__ W2, const float* __restrict__ b2,
    float* __restrict__ p_copy, float* __restrict__ lam) {
  extern __shared__ uint4 smem[];
  uint4* Bs = smem;          // 4096 chunks = 64 KB
  uint4* Ub = smem + 4096;   // 1024 chunks = 16 KB: t*64 + (slot ^ t)

  const int tid = threadIdx.x;
  const int lane = tid & 63;
  const int w = tid >> 6;    // 0..7
  const int lm = lane & 15;
  const int lg = lane >> 4;
  const int bid = blockIdx.x;
  const int b = bid & 7;             // XCD-affine
  const int t0 = (bid >> 3) * 16;

  const int t_local = w * 2 + (lm >> 3);
  const int t = t0 + t_local;
  const int ctv = c_t[b * NT + t];
  const bool valid = ctv >= 0;
  const int c = valid ? ctv : 0;

  const int myt = t0 + lm;
  const int ctv2 = c_t[b * NT + myt];
  const int myc = ctv2 < 0 ? 0 : ctv2;

  f32x4 accB[2];
#pragma unroll
  for (int f = 0; f < 2; ++f) {
    const float4 bv = *(const float4*)&b1[(w * 2 + f) * 16 + lg * 4];
    accB[f][0] = bv.x; accB[f][1] = bv.y; accB[f][2] = bv.z; accB[f][3] = bv.w;
  }

  // ---- base hb0: issue loads FIRST (older than staging in vmcnt FIFO) ----
  float4 f0a[5], f1a[5];
  uint4 bb[10];
#pragma unroll
  for (int i = 0; i < 5; ++i) {
    const int gk = i * 4 + lg;  // 0..19
    const float* asrc = &hs[((size_t)b * NT + myt) * NH + gk * 8];
    f0a[i] = *(const float4*)asrc;
    f1a[i] = *(const float4*)(asrc + 4);
  }
#pragma unroll
  for (int i = 0; i < 5; ++i) {
    const int gk = i * 4 + lg;
#pragma unroll
    for (int f = 0; f < 2; ++f) {
      const int n = (w * 2 + f) * 16 + lm;
      bb[i * 2 + f] = imgB[(size_t)gk * 256 + (n ^ (gk & 7))];
    }
  }

  // ---- staging: issue global_load_lds (stays in flight under base) ----
#pragma unroll
  for (int it = 0; it < 8; ++it) {
    const int off = (w * 8 + it) * 64;
    __builtin_amdgcn_global_load_lds(
        (const __attribute__((address_space(1))) void*)(imgEx + off + lane),
        (__attribute__((address_space(3))) void*)(Bs + off), 16, 0, 0);
  }

  // ---- base hb0 compute (waits vmcnt(8): hb0 loads done, stage in flight) ----
#pragma unroll
  for (int i = 0; i < 5; ++i) {
    union { uint4 u; bf16x8 v; } A;
    A.u = pack8(f0a[i], f1a[i]);
#pragma unroll
    for (int f = 0; f < 2; ++f) {
      union { uint4 u; bf16x8 v; } B2;
      B2.u = bb[i * 2 + f];
      accB[f] = __builtin_amdgcn_mfma_f32_16x16x32_bf16(B2.v, A.v, accB[f], 0, 0, 0);
    }
  }

  // ---- base hb1: loads + compute ----
#pragma unroll
  for (int i = 0; i < 5; ++i) {
    const int gk = 20 + i * 4 + lg;  // 20..39
    const float* asrc = (gk < 32)
        ? &hs[((size_t)b * NT + myt) * NH + gk * 8]
        : &col[((size_t)b * NL + myc) * NF + (gk - 32) * 8];
    f0a[i] = *(const float4*)asrc;
    f1a[i] = *(const float4*)(asrc + 4);
  }
#pragma unroll
  for (int i = 0; i < 5; ++i) {
    const int gk = 20 + i * 4 + lg;
#pragma unroll
    for (int f = 0; f < 2; ++f) {
      const int n = (w * 2 + f) * 16 + lm;
      bb[i * 2 + f] = imgB[(size_t)gk * 256 + (n ^ (gk & 7))];
    }
  }
#pragma unroll
  for (int i = 0; i < 5; ++i) {
    union { uint4 u; bf16x8 v; } A;
    A.u = pack8(f0a[i], f1a[i]);
#pragma unroll
    for (int f = 0; f < 2; ++f) {
      union { uint4 u; bf16x8 v; } B2;
      B2.u = bb[i * 2 + f];
      accB[f] = __builtin_amdgcn_mfma_f32_16x16x32_bf16(B2.v, A.v, accB[f], 0, 0, 0);
    }
  }

  // ---- Ub deposit: row lm, slot s = (w*2+f)*4+lg, phys = s ^ lm ----
#pragma unroll
  for (int f = 0; f < 2; ++f) {
    union { uint4 u; f32x4 v; } o;
    o.v = accB[f];
    Ub[lm * 64 + (((w * 2 + f) * 4 + lg) ^ lm)] = o.u;
  }

  // ---- ex gather (lane-private row: k = lm&7, col c of its t) + pack ----
  const float* arow = &ex[(((size_t)b * NK + (lm & 7)) * NL + c) * NE];
  uint4 aPk[4];
  {
    float4 pf[8];
#pragma unroll
    for (int ks = 0; ks < 4; ++ks) {
      const int g = ks * 4 + lg;
      pf[2 * ks] = *(const float4*)(arow + g * 8);
      pf[2 * ks + 1] = *(const float4*)(arow + g * 8 + 4);
    }
#pragma unroll
    for (int ks = 0; ks < 4; ++ks) aPk[ks] = pack8(pf[2 * ks], pf[2 * ks + 1]);
  }

  __syncthreads();

  // ---- phase 4: two sequential half-N passes, partial dot folded in ----
  const float b2v = b2[0];
  float p = 0.f;
#pragma unroll 1
  for (int half = 0; half < 2; ++half) {
    f32x4 acc[8] = {};
#pragma unroll
    for (int ks = 0; ks < 4; ++ks) {
      const int g = ks * 4 + lg;
      union { uint4 u; bf16x8 v; } A;
      A.u = aPk[ks];
#pragma unroll
      for (int fn = 0; fn < 8; ++fn) {
        const int n = half * 128 + fn * 16 + lm;
        const bf16x8 bfr = *(const bf16x8*)&Bs[g * 256 + (n ^ (g & 7))];
        acc[fn] = __builtin_amdgcn_mfma_f32_16x16x32_bf16(bfr, A.v, acc[fn], 0, 0, 0);
      }
    }
#pragma unroll
    for (int fn = 0; fn < 8; ++fn) {
      const int n0 = half * 128 + fn * 16 + lg * 4;
      union { uint4 u; f32x4 v; } ubv;
      ubv.u = Ub[t_local * 64 + ((half * 32 + fn * 4 + lg) ^ t_local)];
      const float4 w2v = *(const float4*)&W2[n0];
      p += fmaxf(acc[fn][0] + ubv.v[0], 0.f) * w2v.x +
           fmaxf(acc[fn][1] + ubv.v[1], 0.f) * w2v.y +
           fmaxf(acc[fn][2] + ubv.v[2], 0.f) * w2v.z +
           fmaxf(acc[fn][3] + ubv.v[3], 0.f) * w2v.w;
    }
  }
  p += __shfl_xor(p, 16);
  p += __shfl_xor(p, 32);
  const float score = p + b2v;

  float mx = score;
  mx = fmaxf(mx, __shfl_xor(mx, 1));
  mx = fmaxf(mx, __shfl_xor(mx, 2));
  mx = fmaxf(mx, __shfl_xor(mx, 4));
  const float e = __expf(score - mx);
  float s = e;
  s += __shfl_xor(s, 1);
  s += __shfl_xor(s, 2);
  s += __shfl_xor(s, 4);
  const float wgt = valid ? (e / s) : 0.f;

  if (lg == 0) lam[((size_t)b * NT + t0 + w * 2) * NK + lm] = wgt;

  int aav = 0;
  if (lg == 0) aav = aa_ids[((size_t)b * NK + (lm & 7)) * NL + c];

  const int bin = lane & 31;
  const int half = lane >> 5;
  const int src0 = half * 8;
  float pc = 0.f;
#pragma unroll
  for (int k = 0; k < 8; ++k) {
    const int a = __shfl(aav, src0 + k);
    const float ww = __shfl(wgt, src0 + k);
    pc += (a == bin) ? ww : 0.f;
  }
  if (bin < NV)
    p_copy[((size_t)b * NT + t0 + w * 2 + half) * NV + bin] = pc;
}

extern "C" void kernel_launch(void* const* d_in, const int* in_sizes, int n_in,
                              void* d_out, int out_size, void* d_ws, size_t ws_size,
                              hipStream_t stream) {
  const float* hs = (const float*)d_in[0];
  const float* ex = (const float*)d_in[1];
  const float* col = (const float*)d_in[2];
  const int* ct = (const int*)d_in[3];
  const int* aa = (const int*)d_in[4];
  const float* W1 = (const float*)d_in[5];
  const float* b1 = (const float*)d_in[6];
  const float* W2 = (const float*)d_in[7];
  const float* b2 = (const float*)d_in[8];

  uint4* imgEx = (uint4*)d_ws;        // 64 KB
  uint4* imgB = imgEx + 4096;         // 160 KB

  float* p_copy = (float*)d_out;
  float* lam = p_copy + (size_t)NB * NT * NV;

  const size_t lds_bytes = (4096 + 1024) * sizeof(uint4);  // 80 KB

  k_prep<<<56, 64, 0, stream>>>(W1, imgEx, imgB);
  k_mega<<<512, 512, lds_bytes, stream>>>(hs, ex, col, ct, aa, imgEx, imgB,
                                          b1, W2, b2, p_copy, lam);
}